// Round 11
// baseline (928.915 us; speedup 1.0000x reference)
//
#include <hip/hip_runtime.h>

#define K_TPLT 16
#define M_NODES 10
#define DFEAT 128
#define NMAX 7            // supports up to 448 nodes per graph (actual: 400)
#define N_ITER 50
#define NEG_BIG -1e30f
#define LOG2E 1.44269504088896340736f
#define LN2   0.69314718055994530942f

#define EXP2F(x) __builtin_amdgcn_exp2f(x)
#define LOG2F(x) __builtin_amdgcn_logf(x)   // v_log_f32 = log base 2

__global__ void zero_counts_k(int* counts, int G) {
    int g = blockIdx.x * blockDim.x + threadIdx.x;
    if (g < G) counts[g] = 0;
}

__global__ void count_nodes_k(const int* __restrict__ batch, int* counts, int N) {
    int i = blockIdx.x * blockDim.x + threadIdx.x;
    if (i < N) atomicAdd(&counts[batch[i]], 1);
}

__global__ void scan_counts_k(const int* __restrict__ counts, int* starts, int G) {
    __shared__ int sc[1024];
    int t = threadIdx.x;
    for (int g = t; g < G; g += blockDim.x) sc[g] = counts[g];
    __syncthreads();
    for (int g = t; g < G; g += blockDim.x) {
        int s = 0;
        for (int j = 0; j < g; ++j) s += sc[j];
        starts[g] = s;
    }
}

// One 1024-thread block per GRAPH; its 16 waves are the 16 templates.
// Waves are fully independent (no LDS, no barriers) -- the block exists to
// FORCE co-residency (16 waves/CU = 4/SIMD; R7's 1-wave workgroups packed
// only ~2.2/SIMD) and to make all 16 waves stream the SAME x rows
// concurrently (L1/L2 temporal locality; R10's node-split thrashed L2,
// fetch 527 MB). Per-wave algorithm is bit-identical to the verified R7
// kernel: log-domain L (row max 0), fresh per-node row shift per iteration,
// exact g-update with +g2[m], iteration-1 exact via per-column shift csh.
__global__ __launch_bounds__(1024) void sinkhorn_tw_k(
    const float* __restrict__ x, const float* __restrict__ tplt,
    const float* __restrict__ q0, const int* __restrict__ starts,
    const int* __restrict__ counts, float* __restrict__ out, int G)
{
    const int g    = blockIdx.x;
    const int k    = threadIdx.x >> 6;        // wave id = template id
    const int lane = threadIdx.x & 63;

    const int start = starts[g];
    const int count = counts[g];
    const float a   = 1.0f / (float)count;
    const float la2 = -LOG2F((float)count);            // log2(a)

    // lbla[m] = log2_softmax(q0[k,:]) - la2
    const float* qk = q0 + k * M_NODES;
    float lbla[M_NODES];
    {
        float qv[M_NODES];
        float qmax = NEG_BIG;
#pragma unroll
        for (int m = 0; m < M_NODES; ++m) { qv[m] = qk[m]; qmax = fmaxf(qmax, qv[m]); }
        float qs = 0.f;
#pragma unroll
        for (int m = 0; m < M_NODES; ++m) {
            qv[m] = (qv[m] - qmax) * LOG2E;
            qs += EXP2F(qv[m]);
        }
        const float corr = LOG2F(qs);
#pragma unroll
        for (int m = 0; m < M_NODES; ++m) lbla[m] = qv[m] - corr - la2;
    }

    bool act[NMAX];
#pragma unroll
    for (int i = 0; i < NMAX; ++i) act[i] = (lane + i * 64) < count;

    // L[i][m] = (negC * log2e) - nsh_i  (log2 domain, <= 0, row max == 0)
    float L[NMAX][M_NODES];
    float nsh[NMAX];
    float csh[M_NODES];
    {
        const float* Tk = tplt + (size_t)k * M_NODES * DFEAT;
        float x2[NMAX];
        float t2[M_NODES];
#pragma unroll
        for (int i = 0; i < NMAX; ++i) {
            x2[i] = 0.f;
#pragma unroll
            for (int m = 0; m < M_NODES; ++m) L[i][m] = 0.f;
        }
#pragma unroll
        for (int m = 0; m < M_NODES; ++m) t2[m] = 0.f;

        for (int j = 0; j < DFEAT; j += 4) {
            float4 xv[NMAX];
#pragma unroll
            for (int i = 0; i < NMAX; ++i) {
                if (act[i]) {
                    xv[i] = *(const float4*)(x + (size_t)(start + lane + i * 64) * DFEAT + j);
                } else {
                    xv[i].x = xv[i].y = xv[i].z = xv[i].w = 0.f;
                }
                x2[i] += xv[i].x * xv[i].x + xv[i].y * xv[i].y
                       + xv[i].z * xv[i].z + xv[i].w * xv[i].w;
            }
#pragma unroll
            for (int m = 0; m < M_NODES; ++m) {
                const float4 tv = *(const float4*)(Tk + m * DFEAT + j);
                t2[m] += tv.x * tv.x + tv.y * tv.y + tv.z * tv.z + tv.w * tv.w;
#pragma unroll
                for (int i = 0; i < NMAX; ++i) {
                    L[i][m] += xv[i].x * tv.x + xv[i].y * tv.y
                             + xv[i].z * tv.z + xv[i].w * tv.w;
                }
            }
        }
#pragma unroll
        for (int i = 0; i < NMAX; ++i) {
            float mx = NEG_BIG;
#pragma unroll
            for (int m = 0; m < M_NODES; ++m) {
                L[i][m] = (2.f * L[i][m] - x2[i] - t2[m]) * LOG2E;   // negC2
                mx = fmaxf(mx, L[i][m]);
            }
            nsh[i] = mx;
#pragma unroll
            for (int m = 0; m < M_NODES; ++m) L[i][m] -= mx;         // <= 0
        }
        // csh_m = column max of L over active entries (<= 0)
#pragma unroll
        for (int m = 0; m < M_NODES; ++m) {
            float c = NEG_BIG;
#pragma unroll
            for (int i = 0; i < NMAX; ++i) c = act[i] ? fmaxf(c, L[i][m]) : c;
            for (int off = 32; off > 0; off >>= 1) c = fmaxf(c, __shfl_xor(c, off));
            csh[m] = c;
        }
    }

    float g2[M_NODES];

    // ---- iteration 1: g = 0, exact with per-column shift csh ----
    {
        float w0[M_NODES], acc[M_NODES];
#pragma unroll
        for (int m = 0; m < M_NODES; ++m) { w0[m] = EXP2F(csh[m]); acc[m] = 0.f; }
#pragma unroll
        for (int i = 0; i < NMAX; ++i) {
            if (act[i]) {
                float E[M_NODES];
                float D = 0.f;
#pragma unroll
                for (int m = 0; m < M_NODES; ++m) {
                    E[m] = EXP2F(L[i][m] - csh[m]);     // <= 1, col max == 1
                    D = fmaf(E[m], w0[m], D);           // = sum 2^L, >= 1
                }
                const float r = __builtin_amdgcn_rcpf(D);
#pragma unroll
                for (int m = 0; m < M_NODES; ++m) acc[m] = fmaf(E[m], r, acc[m]);
            }
        }
#pragma unroll
        for (int m = 0; m < M_NODES; ++m) {
            float s = acc[m];
            for (int off = 32; off > 0; off >>= 1) s += __shfl_xor(s, off);
            g2[m] = lbla[m] - csh[m] - LOG2F(fmaxf(s, 1e-35f));
        }
    }

    // ---- iterations 2..N_ITER: fresh per-node row shift each time ----
    for (int it = 1; it < N_ITER; ++it) {
        float acc[M_NODES];
#pragma unroll
        for (int m = 0; m < M_NODES; ++m) acc[m] = 0.f;

#pragma unroll
        for (int i = 0; i < NMAX; ++i) {
            if (act[i]) {
                float e[M_NODES];
                float zmax = NEG_BIG;
#pragma unroll
                for (int m = 0; m < M_NODES; ++m) {
                    e[m] = g2[m] + L[i][m];
                    zmax = fmaxf(zmax, e[m]);
                }
                float D = 0.f;
#pragma unroll
                for (int m = 0; m < M_NODES; ++m) { e[m] = EXP2F(e[m] - zmax); D += e[m]; }
                const float r = __builtin_amdgcn_rcpf(D);   // D in [1,10]
#pragma unroll
                for (int m = 0; m < M_NODES; ++m) acc[m] = fmaf(e[m], r, acc[m]);
            }
        }
#pragma unroll
        for (int m = 0; m < M_NODES; ++m) {
            float s = acc[m];
            for (int off = 32; off > 0; off >>= 1) s += __shfl_xor(s, off);
            g2[m] = lbla[m] + g2[m] - LOG2F(fmaxf(s, 1e-35f));   // + g2[m]: exact update
        }
    }

    // ---- epilogue: final f fused with transport cost ----
    // P[n,m] = a * e_m * r_n ; C = -ln2*(L + nsh)
    // per_node = -a*ln2*( nsh_i + r * sum_m e_m L_m )
    float accum = 0.f;
#pragma unroll
    for (int i = 0; i < NMAX; ++i) {
        if (act[i]) {
            float e[M_NODES];
            float zmax = NEG_BIG;
#pragma unroll
            for (int m = 0; m < M_NODES; ++m) {
                e[m] = g2[m] + L[i][m];
                zmax = fmaxf(zmax, e[m]);
            }
            float D = 0.f;
#pragma unroll
            for (int m = 0; m < M_NODES; ++m) { e[m] = EXP2F(e[m] - zmax); D += e[m]; }
            const float r = __builtin_amdgcn_rcpf(D);
            float q = 0.f;
#pragma unroll
            for (int m = 0; m < M_NODES; ++m) q = fmaf(e[m], L[i][m], q);
            accum += nsh[i] + q * r;
        }
    }
    for (int off = 32; off > 0; off >>= 1) accum += __shfl_xor(accum, off);
    if (lane == 0) out[(size_t)g * K_TPLT + k] = -a * LN2 * accum;
}

extern "C" void kernel_launch(void* const* d_in, const int* in_sizes, int n_in,
                              void* d_out, int out_size, void* d_ws, size_t ws_size,
                              hipStream_t stream) {
    const float* x    = (const float*)d_in[0];
    const float* tplt = (const float*)d_in[1];
    const float* q0   = (const float*)d_in[2];
    const int* batch  = (const int*)d_in[3];
    const int N = in_sizes[3];
    const int G = out_size / K_TPLT;

    int* counts = (int*)d_ws;
    int* starts = counts + G;

    zero_counts_k<<<(G + 255) / 256, 256, 0, stream>>>(counts, G);
    count_nodes_k<<<(N + 255) / 256, 256, 0, stream>>>(batch, counts, N);
    scan_counts_k<<<1, 256, 0, stream>>>(counts, starts, G);
    sinkhorn_tw_k<<<G, 1024, 0, stream>>>(x, tplt, q0, starts, counts,
                                          (float*)d_out, G);
}

// Round 15
// 518.440 us; speedup vs baseline: 1.7918x; 1.7918x over previous
//
#include <hip/hip_runtime.h>

#define K_TPLT 16
#define M_NODES 10
#define DFEAT 128
#define NMAX 7            // supports up to 448 nodes per graph (actual: 400)
#define N_ITER 50
#define NEG_BIG -1e30f
#define LOG2E 1.44269504088896340736f
#define LN2   0.69314718055994530942f

#define EXP2F(x) __builtin_amdgcn_exp2f(x)
#define LOG2F(x) __builtin_amdgcn_logf(x)   // v_log_f32 = log base 2

__global__ void zero_counts_k(int* counts, int G) {
    int g = blockIdx.x * blockDim.x + threadIdx.x;
    if (g < G) counts[g] = 0;
}

__global__ void count_nodes_k(const int* __restrict__ batch, int* counts, int N) {
    int i = blockIdx.x * blockDim.x + threadIdx.x;
    if (i < N) atomicAdd(&counts[batch[i]], 1);
}

__global__ void scan_counts_k(const int* __restrict__ counts, int* starts, int G) {
    __shared__ int sc[1024];
    int t = threadIdx.x;
    for (int g = t; g < G; g += blockDim.x) sc[g] = counts[g];
    __syncthreads();
    for (int g = t; g < G; g += blockDim.x) {
        int s = 0;
        for (int j = 0; j < g; ++j) s += sc[j];
        starts[g] = s;
    }
}

// Wave reductions: strides 1/2/4/8 via DPP-fused VALU (quad_perm xor1=0xB1,
// xor2=0x4E, row_half_mirror=0x141, row_mirror=0x140), strides 16/32 via
// shfl_xor. DPP ctrl must be an immediate -> template parameter.
template <int CTRL>
__device__ __forceinline__ float dpp_add(float v) {
    return v + __int_as_float(__builtin_amdgcn_update_dpp(
        0, __float_as_int(v), CTRL, 0xF, 0xF, true));
}
__device__ __forceinline__ float wred_add(float v) {
    v = dpp_add<0xB1>(v);   // xor 1 (quad_perm [1,0,3,2])
    v = dpp_add<0x4E>(v);   // xor 2 (quad_perm [2,3,0,1])
    v = dpp_add<0x141>(v);  // pair within 8 (row_half_mirror)
    v = dpp_add<0x140>(v);  // pair within 16 (row_mirror)
    v += __shfl_xor(v, 16);
    v += __shfl_xor(v, 32);
    return v;
}
template <int CTRL>
__device__ __forceinline__ float dpp_max(float v) {
    return fmaxf(v, __int_as_float(__builtin_amdgcn_update_dpp(
        0, __float_as_int(v), CTRL, 0xF, 0xF, true)));
}
__device__ __forceinline__ float wred_max(float v) {
    v = dpp_max<0xB1>(v);
    v = dpp_max<0x4E>(v);
    v = dpp_max<0x141>(v);
    v = dpp_max<0x140>(v);
    v = fmaxf(v, __shfl_xor(v, 16));
    v = fmaxf(v, __shfl_xor(v, 32));
    return v;
}

// One wave per (graph, template) problem — the R8-verified algorithm
// (410 us, passed): log-domain L (row max 0), fresh per-node row shift per
// iteration, exact g-update with +g2[m], iteration-1 exact via per-column
// shift csh. Only change vs R8: DPP-accelerated reductions.
__global__ __launch_bounds__(64) void sinkhorn_tw_k(
    const float* __restrict__ x, const float* __restrict__ tplt,
    const float* __restrict__ q0, const int* __restrict__ starts,
    const int* __restrict__ counts, float* __restrict__ out, int G)
{
    const int bid  = blockIdx.x;
    const int g    = bid % G;      // same-g blocks land on same XCD (G % 8 == 0)
    const int k    = bid / G;
    const int lane = threadIdx.x;

    const int start = starts[g];
    const int count = counts[g];
    const float a   = 1.0f / (float)count;
    const float la2 = -LOG2F((float)count);            // log2(a)

    // lbla[m] = log2_softmax(q0[k,:]) - la2
    const float* qk = q0 + k * M_NODES;
    float lbla[M_NODES];
    {
        float qv[M_NODES];
        float qmax = NEG_BIG;
#pragma unroll
        for (int m = 0; m < M_NODES; ++m) { qv[m] = qk[m]; qmax = fmaxf(qmax, qv[m]); }
        float qs = 0.f;
#pragma unroll
        for (int m = 0; m < M_NODES; ++m) {
            qv[m] = (qv[m] - qmax) * LOG2E;
            qs += EXP2F(qv[m]);
        }
        const float corr = LOG2F(qs);
#pragma unroll
        for (int m = 0; m < M_NODES; ++m) lbla[m] = qv[m] - corr - la2;
    }

    bool act[NMAX];
#pragma unroll
    for (int i = 0; i < NMAX; ++i) act[i] = (lane + i * 64) < count;

    // L[i][m] = (negC * log2e) - nsh_i  (log2 domain, <= 0, row max == 0)
    float L[NMAX][M_NODES];
    float nsh[NMAX];
    float csh[M_NODES];
    {
        const float* Tk = tplt + (size_t)k * M_NODES * DFEAT;
        float x2[NMAX];
        float t2[M_NODES];
#pragma unroll
        for (int i = 0; i < NMAX; ++i) {
            x2[i] = 0.f;
#pragma unroll
            for (int m = 0; m < M_NODES; ++m) L[i][m] = 0.f;
        }
#pragma unroll
        for (int m = 0; m < M_NODES; ++m) t2[m] = 0.f;

        for (int j = 0; j < DFEAT; j += 4) {
            float4 xv[NMAX];
#pragma unroll
            for (int i = 0; i < NMAX; ++i) {
                if (act[i]) {
                    xv[i] = *(const float4*)(x + (size_t)(start + lane + i * 64) * DFEAT + j);
                } else {
                    xv[i].x = xv[i].y = xv[i].z = xv[i].w = 0.f;
                }
                x2[i] += xv[i].x * xv[i].x + xv[i].y * xv[i].y
                       + xv[i].z * xv[i].z + xv[i].w * xv[i].w;
            }
#pragma unroll
            for (int m = 0; m < M_NODES; ++m) {
                const float4 tv = *(const float4*)(Tk + m * DFEAT + j);
                t2[m] += tv.x * tv.x + tv.y * tv.y + tv.z * tv.z + tv.w * tv.w;
#pragma unroll
                for (int i = 0; i < NMAX; ++i) {
                    L[i][m] += xv[i].x * tv.x + xv[i].y * tv.y
                             + xv[i].z * tv.z + xv[i].w * tv.w;
                }
            }
        }
#pragma unroll
        for (int i = 0; i < NMAX; ++i) {
            float mx = NEG_BIG;
#pragma unroll
            for (int m = 0; m < M_NODES; ++m) {
                L[i][m] = (2.f * L[i][m] - x2[i] - t2[m]) * LOG2E;   // negC2
                mx = fmaxf(mx, L[i][m]);
            }
            nsh[i] = mx;
#pragma unroll
            for (int m = 0; m < M_NODES; ++m) L[i][m] -= mx;         // <= 0
        }
        // csh_m = column max of L over active entries (<= 0)
#pragma unroll
        for (int m = 0; m < M_NODES; ++m) {
            float c = NEG_BIG;
#pragma unroll
            for (int i = 0; i < NMAX; ++i) c = act[i] ? fmaxf(c, L[i][m]) : c;
            csh[m] = wred_max(c);
        }
    }

    float g2[M_NODES];

    // ---- iteration 1: g = 0, exact with per-column shift csh ----
    {
        float w0[M_NODES], acc[M_NODES];
#pragma unroll
        for (int m = 0; m < M_NODES; ++m) { w0[m] = EXP2F(csh[m]); acc[m] = 0.f; }
#pragma unroll
        for (int i = 0; i < NMAX; ++i) {
            if (act[i]) {
                float E[M_NODES];
                float D = 0.f;
#pragma unroll
                for (int m = 0; m < M_NODES; ++m) {
                    E[m] = EXP2F(L[i][m] - csh[m]);     // <= 1, col max == 1
                    D = fmaf(E[m], w0[m], D);           // = sum 2^L, >= 1
                }
                const float r = __builtin_amdgcn_rcpf(D);
#pragma unroll
                for (int m = 0; m < M_NODES; ++m) acc[m] = fmaf(E[m], r, acc[m]);
            }
        }
#pragma unroll
        for (int m = 0; m < M_NODES; ++m) {
            const float s = wred_add(acc[m]);
            g2[m] = lbla[m] - csh[m] - LOG2F(fmaxf(s, 1e-35f));
        }
    }

    // ---- iterations 2..N_ITER: fresh per-node row shift each time ----
    for (int it = 1; it < N_ITER; ++it) {
        float acc[M_NODES];
#pragma unroll
        for (int m = 0; m < M_NODES; ++m) acc[m] = 0.f;

#pragma unroll
        for (int i = 0; i < NMAX; ++i) {
            if (act[i]) {
                float e[M_NODES];
                float zmax = NEG_BIG;
#pragma unroll
                for (int m = 0; m < M_NODES; ++m) {
                    e[m] = g2[m] + L[i][m];
                    zmax = fmaxf(zmax, e[m]);
                }
                float D = 0.f;
#pragma unroll
                for (int m = 0; m < M_NODES; ++m) { e[m] = EXP2F(e[m] - zmax); D += e[m]; }
                const float r = __builtin_amdgcn_rcpf(D);   // D in [1,10]
#pragma unroll
                for (int m = 0; m < M_NODES; ++m) acc[m] = fmaf(e[m], r, acc[m]);
            }
        }
#pragma unroll
        for (int m = 0; m < M_NODES; ++m) {
            const float s = wred_add(acc[m]);
            g2[m] = lbla[m] + g2[m] - LOG2F(fmaxf(s, 1e-35f));   // exact update
        }
    }

    // ---- epilogue: final f fused with transport cost ----
    // P[n,m] = a * e_m * r_n ; C = -ln2*(L + nsh)
    // per_node = -a*ln2*( nsh_i + r * sum_m e_m L_m )
    float accum = 0.f;
#pragma unroll
    for (int i = 0; i < NMAX; ++i) {
        if (act[i]) {
            float e[M_NODES];
            float zmax = NEG_BIG;
#pragma unroll
            for (int m = 0; m < M_NODES; ++m) {
                e[m] = g2[m] + L[i][m];
                zmax = fmaxf(zmax, e[m]);
            }
            float D = 0.f;
#pragma unroll
            for (int m = 0; m < M_NODES; ++m) { e[m] = EXP2F(e[m] - zmax); D += e[m]; }
            const float r = __builtin_amdgcn_rcpf(D);
            float q = 0.f;
#pragma unroll
            for (int m = 0; m < M_NODES; ++m) q = fmaf(e[m], L[i][m], q);
            accum += nsh[i] + q * r;
        }
    }
    accum = wred_add(accum);
    if (lane == 0) out[(size_t)g * K_TPLT + k] = -a * LN2 * accum;
}

extern "C" void kernel_launch(void* const* d_in, const int* in_sizes, int n_in,
                              void* d_out, int out_size, void* d_ws, size_t ws_size,
                              hipStream_t stream) {
    const float* x    = (const float*)d_in[0];
    const float* tplt = (const float*)d_in[1];
    const float* q0   = (const float*)d_in[2];
    const int* batch  = (const int*)d_in[3];
    const int N = in_sizes[3];
    const int G = out_size / K_TPLT;

    int* counts = (int*)d_ws;
    int* starts = counts + G;

    zero_counts_k<<<(G + 255) / 256, 256, 0, stream>>>(counts, G);
    count_nodes_k<<<(N + 255) / 256, 256, 0, stream>>>(batch, counts, N);
    scan_counts_k<<<1, 256, 0, stream>>>(counts, starts, G);
    sinkhorn_tw_k<<<G * K_TPLT, 64, 0, stream>>>(x, tplt, q0, starts, counts,
                                                 (float*)d_out, G);
}

// Round 17
// 486.215 us; speedup vs baseline: 1.9105x; 1.0663x over previous
//
#include <hip/hip_runtime.h>

#define K_TPLT 16
#define M_NODES 10
#define DFEAT 128
#define NMAX 7            // supports up to 448 nodes per graph (actual: 400)
#define NPROB 2           // problems (k, k+8) per wave
#define N_ITER 50
#define NEG_BIG -1e30f
#define LOG2E 1.44269504088896340736f
#define LN2   0.69314718055994530942f

#define EXP2F(x) __builtin_amdgcn_exp2f(x)
#define LOG2F(x) __builtin_amdgcn_logf(x)   // v_log_f32 = log base 2

__global__ void zero_counts_k(int* counts, int G) {
    int g = blockIdx.x * blockDim.x + threadIdx.x;
    if (g < G) counts[g] = 0;
}

__global__ void count_nodes_k(const int* __restrict__ batch, int* counts, int N) {
    int i = blockIdx.x * blockDim.x + threadIdx.x;
    if (i < N) atomicAdd(&counts[batch[i]], 1);
}

__global__ void scan_counts_k(const int* __restrict__ counts, int* starts, int G) {
    __shared__ int sc[1024];
    int t = threadIdx.x;
    for (int g = t; g < G; g += blockDim.x) sc[g] = counts[g];
    __syncthreads();
    for (int g = t; g < G; g += blockDim.x) {
        int s = 0;
        for (int j = 0; j < g; ++j) s += sc[j];
        starts[g] = s;
    }
}

template <int CTRL>
__device__ __forceinline__ float dpp_add(float v) {
    return v + __int_as_float(__builtin_amdgcn_update_dpp(
        0, __float_as_int(v), CTRL, 0xF, 0xF, true));
}
__device__ __forceinline__ float wred_add(float v) {
    v = dpp_add<0xB1>(v);
    v = dpp_add<0x4E>(v);
    v = dpp_add<0x141>(v);
    v = dpp_add<0x140>(v);
    v += __shfl_xor(v, 16);
    v += __shfl_xor(v, 32);
    return v;
}
template <int CTRL>
__device__ __forceinline__ float dpp_max(float v) {
    return fmaxf(v, __int_as_float(__builtin_amdgcn_update_dpp(
        0, __float_as_int(v), CTRL, 0xF, 0xF, true)));
}
__device__ __forceinline__ float wred_max(float v) {
    v = dpp_max<0xB1>(v);
    v = dpp_max<0x4E>(v);
    v = dpp_max<0x141>(v);
    v = dpp_max<0x140>(v);
    v = fmaxf(v, __shfl_xor(v, 16));
    v = fmaxf(v, __shfl_xor(v, 32));
    return v;
}

// TWO (g,k) problems per wave: (g, k0) and (g, k0+8). Same graph -> the x
// float4 loads, x2, start/count/act are shared; the two Sinkhorn chains are
// fully independent -> 2x ILP on the latency-bound exp2/rcp chains (R15 was
// grid-limited at ~2.2 waves/SIMD, 43% issue efficiency). Per-problem math
// is the R15-VERIFIED scheme verbatim: log-domain L (row max 0), fresh
// per-node row shift each iteration, exact g-update with +g2[m], iteration-1
// exact via per-column shift csh. Multiplicative variants (R12/13/16)
// permanently abandoned: fp32 linear state cannot absorb the +-300 log2-unit
// dynamic range; the per-iteration re-exponentiation is load-bearing.
// nsh is pre-folded into a per-lane scalar (nsum) to cut register pressure.
__global__ __launch_bounds__(64) void sinkhorn_tw_k(
    const float* __restrict__ x, const float* __restrict__ tplt,
    const float* __restrict__ q0, const int* __restrict__ starts,
    const int* __restrict__ counts, float* __restrict__ out, int G)
{
    const int bid  = blockIdx.x;
    const int g    = bid % G;      // same-g blocks land on same XCD (G % 8 == 0)
    const int k0   = bid / G;      // k0 in [0,8); problems k0 and k0+8
    const int lane = threadIdx.x;

    const int start = starts[g];
    const int count = counts[g];
    const float a   = 1.0f / (float)count;
    const float la2 = -LOG2F((float)count);            // log2(a)

    // lbla[p][m] = log2_softmax(q0[k,:]) - la2
    float lbla[NPROB][M_NODES];
#pragma unroll
    for (int p = 0; p < NPROB; ++p) {
        const float* qk = q0 + (k0 + 8 * p) * M_NODES;
        float qv[M_NODES];
        float qmax = NEG_BIG;
#pragma unroll
        for (int m = 0; m < M_NODES; ++m) { qv[m] = qk[m]; qmax = fmaxf(qmax, qv[m]); }
        float qs = 0.f;
#pragma unroll
        for (int m = 0; m < M_NODES; ++m) {
            qv[m] = (qv[m] - qmax) * LOG2E;
            qs += EXP2F(qv[m]);
        }
        const float corr = LOG2F(qs);
#pragma unroll
        for (int m = 0; m < M_NODES; ++m) lbla[p][m] = qv[m] - corr - la2;
    }

    bool act[NMAX];
#pragma unroll
    for (int i = 0; i < NMAX; ++i) act[i] = (lane + i * 64) < count;

    // L[p][i][m] = (negC * log2e) - nsh_i  (log2 domain, <= 0, row max == 0)
    float L[NPROB][NMAX][M_NODES];
    float nsum[NPROB];             // per-lane sum of nsh_i over active i
    float csh[NPROB][M_NODES];
    {
        const float* Tk0 = tplt + (size_t)k0 * M_NODES * DFEAT;
        const float* Tk1 = tplt + (size_t)(k0 + 8) * M_NODES * DFEAT;
        float x2[NMAX];
        float t2[NPROB][M_NODES];
#pragma unroll
        for (int i = 0; i < NMAX; ++i) {
            x2[i] = 0.f;
#pragma unroll
            for (int p = 0; p < NPROB; ++p)
#pragma unroll
                for (int m = 0; m < M_NODES; ++m) L[p][i][m] = 0.f;
        }
#pragma unroll
        for (int p = 0; p < NPROB; ++p)
#pragma unroll
            for (int m = 0; m < M_NODES; ++m) t2[p][m] = 0.f;

        for (int j = 0; j < DFEAT; j += 4) {
            float4 xv[NMAX];
#pragma unroll
            for (int i = 0; i < NMAX; ++i) {
                if (act[i]) {
                    xv[i] = *(const float4*)(x + (size_t)(start + lane + i * 64) * DFEAT + j);
                } else {
                    xv[i].x = xv[i].y = xv[i].z = xv[i].w = 0.f;
                }
                x2[i] += xv[i].x * xv[i].x + xv[i].y * xv[i].y
                       + xv[i].z * xv[i].z + xv[i].w * xv[i].w;
            }
#pragma unroll
            for (int m = 0; m < M_NODES; ++m) {
                const float4 tv0 = *(const float4*)(Tk0 + m * DFEAT + j);
                const float4 tv1 = *(const float4*)(Tk1 + m * DFEAT + j);
                t2[0][m] += tv0.x * tv0.x + tv0.y * tv0.y + tv0.z * tv0.z + tv0.w * tv0.w;
                t2[1][m] += tv1.x * tv1.x + tv1.y * tv1.y + tv1.z * tv1.z + tv1.w * tv1.w;
#pragma unroll
                for (int i = 0; i < NMAX; ++i) {
                    L[0][i][m] += xv[i].x * tv0.x + xv[i].y * tv0.y
                                + xv[i].z * tv0.z + xv[i].w * tv0.w;
                    L[1][i][m] += xv[i].x * tv1.x + xv[i].y * tv1.y
                                + xv[i].z * tv1.z + xv[i].w * tv1.w;
                }
            }
        }
#pragma unroll
        for (int p = 0; p < NPROB; ++p) {
            nsum[p] = 0.f;
#pragma unroll
            for (int i = 0; i < NMAX; ++i) {
                float mx = NEG_BIG;
#pragma unroll
                for (int m = 0; m < M_NODES; ++m) {
                    L[p][i][m] = (2.f * L[p][i][m] - x2[i] - t2[p][m]) * LOG2E;  // negC2
                    mx = fmaxf(mx, L[p][i][m]);
                }
                if (act[i]) nsum[p] += mx;
#pragma unroll
                for (int m = 0; m < M_NODES; ++m) L[p][i][m] -= mx;   // <= 0
            }
#pragma unroll
            for (int m = 0; m < M_NODES; ++m) {
                float c = NEG_BIG;
#pragma unroll
                for (int i = 0; i < NMAX; ++i) c = act[i] ? fmaxf(c, L[p][i][m]) : c;
                csh[p][m] = wred_max(c);
            }
        }
    }

    float g2[NPROB][M_NODES];

    // ---- iteration 1: g = 0, exact with per-column shift csh ----
#pragma unroll
    for (int p = 0; p < NPROB; ++p) {
        float w0[M_NODES], acc[M_NODES];
#pragma unroll
        for (int m = 0; m < M_NODES; ++m) { w0[m] = EXP2F(csh[p][m]); acc[m] = 0.f; }
#pragma unroll
        for (int i = 0; i < NMAX; ++i) {
            if (act[i]) {
                float E[M_NODES];
                float D = 0.f;
#pragma unroll
                for (int m = 0; m < M_NODES; ++m) {
                    E[m] = EXP2F(L[p][i][m] - csh[p][m]);   // <= 1, col max == 1
                    D = fmaf(E[m], w0[m], D);               // = sum 2^L, >= 1
                }
                const float r = __builtin_amdgcn_rcpf(D);
#pragma unroll
                for (int m = 0; m < M_NODES; ++m) acc[m] = fmaf(E[m], r, acc[m]);
            }
        }
#pragma unroll
        for (int m = 0; m < M_NODES; ++m) {
            const float s = wred_add(acc[m]);
            g2[p][m] = lbla[p][m] - csh[p][m] - LOG2F(fmaxf(s, 1e-35f));
        }
    }

    // ---- iterations 2..N_ITER: fresh per-node row shift; chains interleaved ----
    for (int it = 1; it < N_ITER; ++it) {
        float acc[NPROB][M_NODES];
#pragma unroll
        for (int p = 0; p < NPROB; ++p)
#pragma unroll
            for (int m = 0; m < M_NODES; ++m) acc[p][m] = 0.f;

#pragma unroll
        for (int i = 0; i < NMAX; ++i) {
            if (act[i]) {
#pragma unroll
                for (int p = 0; p < NPROB; ++p) {
                    float e[M_NODES];
                    float zmax = NEG_BIG;
#pragma unroll
                    for (int m = 0; m < M_NODES; ++m) {
                        e[m] = g2[p][m] + L[p][i][m];
                        zmax = fmaxf(zmax, e[m]);
                    }
                    float D = 0.f;
#pragma unroll
                    for (int m = 0; m < M_NODES; ++m) { e[m] = EXP2F(e[m] - zmax); D += e[m]; }
                    const float r = __builtin_amdgcn_rcpf(D);   // D in [1,10]
#pragma unroll
                    for (int m = 0; m < M_NODES; ++m) acc[p][m] = fmaf(e[m], r, acc[p][m]);
                }
            }
        }
#pragma unroll
        for (int p = 0; p < NPROB; ++p)
#pragma unroll
            for (int m = 0; m < M_NODES; ++m) {
                const float s = wred_add(acc[p][m]);
                g2[p][m] = lbla[p][m] + g2[p][m] - LOG2F(fmaxf(s, 1e-35f));  // exact update
            }
    }

    // ---- epilogue: final f fused with transport cost ----
    // per_node = -a*ln2*( nsh_i + r * sum_m e_m L_m ); nsh pre-summed in nsum
#pragma unroll
    for (int p = 0; p < NPROB; ++p) {
        float accum = nsum[p];
#pragma unroll
        for (int i = 0; i < NMAX; ++i) {
            if (act[i]) {
                float e[M_NODES];
                float zmax = NEG_BIG;
#pragma unroll
                for (int m = 0; m < M_NODES; ++m) {
                    e[m] = g2[p][m] + L[p][i][m];
                    zmax = fmaxf(zmax, e[m]);
                }
                float D = 0.f;
#pragma unroll
                for (int m = 0; m < M_NODES; ++m) { e[m] = EXP2F(e[m] - zmax); D += e[m]; }
                const float r = __builtin_amdgcn_rcpf(D);
                float q = 0.f;
#pragma unroll
                for (int m = 0; m < M_NODES; ++m) q = fmaf(e[m], L[p][i][m], q);
                accum += q * r;
            }
        }
        accum = wred_add(accum);
        if (lane == 0) out[(size_t)g * K_TPLT + (k0 + 8 * p)] = -a * LN2 * accum;
    }
}

extern "C" void kernel_launch(void* const* d_in, const int* in_sizes, int n_in,
                              void* d_out, int out_size, void* d_ws, size_t ws_size,
                              hipStream_t stream) {
    const float* x    = (const float*)d_in[0];
    const float* tplt = (const float*)d_in[1];
    const float* q0   = (const float*)d_in[2];
    const int* batch  = (const int*)d_in[3];
    const int N = in_sizes[3];
    const int G = out_size / K_TPLT;

    int* counts = (int*)d_ws;
    int* starts = counts + G;

    zero_counts_k<<<(G + 255) / 256, 256, 0, stream>>>(counts, G);
    count_nodes_k<<<(N + 255) / 256, 256, 0, stream>>>(batch, counts, N);
    scan_counts_k<<<1, 256, 0, stream>>>(counts, starts, G);
    sinkhorn_tw_k<<<G * (K_TPLT / 2), 64, 0, stream>>>(x, tplt, q0, starts, counts,
                                                       (float*)d_out, G);
}

// Round 18
// 455.386 us; speedup vs baseline: 2.0398x; 1.0677x over previous
//
#include <hip/hip_runtime.h>

#define K_TPLT 16
#define M_NODES 10
#define M2 5              // float2 pairs per problem
#define DFEAT 128
#define NMAX 7            // supports up to 448 nodes per graph (actual: 400)
#define NPROB 2           // problems (k, k+8) per wave
#define N_ITER 50
#define NEG_BIG -1e30f
#define LOG2E 1.44269504088896340736f
#define LN2   0.69314718055994530942f

#define EXP2F(x) __builtin_amdgcn_exp2f(x)
#define LOG2F(x) __builtin_amdgcn_logf(x)   // v_log_f32 = log base 2

typedef float v2f __attribute__((ext_vector_type(2)));

__global__ void zero_counts_k(int* counts, int G) {
    int g = blockIdx.x * blockDim.x + threadIdx.x;
    if (g < G) counts[g] = 0;
}

__global__ void count_nodes_k(const int* __restrict__ batch, int* counts, int N) {
    int i = blockIdx.x * blockDim.x + threadIdx.x;
    if (i < N) atomicAdd(&counts[batch[i]], 1);
}

__global__ void scan_counts_k(const int* __restrict__ counts, int* starts, int G) {
    __shared__ int sc[1024];
    int t = threadIdx.x;
    for (int g = t; g < G; g += blockDim.x) sc[g] = counts[g];
    __syncthreads();
    for (int g = t; g < G; g += blockDim.x) {
        int s = 0;
        for (int j = 0; j < g; ++j) s += sc[j];
        starts[g] = s;
    }
}

template <int CTRL>
__device__ __forceinline__ float dpp_add(float v) {
    return v + __int_as_float(__builtin_amdgcn_update_dpp(
        0, __float_as_int(v), CTRL, 0xF, 0xF, true));
}
// Full wave sum, pure VALU: 4 row steps (each 16-lane row -> row sum S_r),
// then row_bcast15 (row3 += S2 -> S2+S3; row1 += S0) and row_bcast31
// (rows>=2 += lane31 = S0+S1) -> lane 63 holds S0+S1+S2+S3. readlane(63)
// broadcasts the total to all lanes via SGPR. No DS ops.
__device__ __forceinline__ float wred_add_u(float v) {
    v = dpp_add<0xB1>(v);    // quad_perm xor1
    v = dpp_add<0x4E>(v);    // quad_perm xor2
    v = dpp_add<0x141>(v);   // row_half_mirror
    v = dpp_add<0x140>(v);   // row_mirror -> row sums
    v = dpp_add<0x142>(v);   // row_bcast15
    v = dpp_add<0x143>(v);   // row_bcast31 -> lane63 = total
    return __int_as_float(__builtin_amdgcn_readlane(__float_as_int(v), 63));
}
template <int CTRL>
__device__ __forceinline__ float dpp_max(float v) {
    return fmaxf(v, __int_as_float(__builtin_amdgcn_update_dpp(
        0, __float_as_int(v), CTRL, 0xF, 0xF, true)));
}
__device__ __forceinline__ float wred_max(float v) {   // setup-only, verified path
    v = dpp_max<0xB1>(v);
    v = dpp_max<0x4E>(v);
    v = dpp_max<0x141>(v);
    v = dpp_max<0x140>(v);
    v = fmaxf(v, __shfl_xor(v, 16));
    v = fmaxf(v, __shfl_xor(v, 32));
    return v;
}
__device__ __forceinline__ v2f v2max(v2f a, v2f b) { return __builtin_elementwise_max(a, b); }
__device__ __forceinline__ float dot4(const float4& a, const float4& b) {
    return a.x * b.x + a.y * b.y + a.z * b.z + a.w * b.w;
}

// TWO (g,k) problems per wave: (g,k0) and (g,k0+8); x loads/x2/act shared.
// Per-problem math is the R15/R17-VERIFIED scheme: log-domain L (row max 0),
// fresh per-node row shift every iteration, exact g-update with +g2, exact
// iteration-1 via per-column shift csh. This round: iteration state held as
// v2f pairs (v_pk_*_f32 packed VALU) and reductions all-DPP (no ds_swizzle).
__global__ __launch_bounds__(64) void sinkhorn_tw_k(
    const float* __restrict__ x, const float* __restrict__ tplt,
    const float* __restrict__ q0, const int* __restrict__ starts,
    const int* __restrict__ counts, float* __restrict__ out, int G)
{
    const int bid  = blockIdx.x;
    const int g    = bid % G;      // same-g blocks land on same XCD (G % 8 == 0)
    const int k0   = bid / G;      // k0 in [0,8); problems k0 and k0+8
    const int lane = threadIdx.x;

    const int start = starts[g];
    const int count = counts[g];
    const float a   = 1.0f / (float)count;
    const float la2 = -LOG2F((float)count);            // log2(a)

    // lbla[p][m] = log2_softmax(q0[k,:]) - la2  (stored as v2f pairs)
    v2f lblav[NPROB][M2];
#pragma unroll
    for (int p = 0; p < NPROB; ++p) {
        const float* qk = q0 + (k0 + 8 * p) * M_NODES;
        float qv[M_NODES];
        float qmax = NEG_BIG;
#pragma unroll
        for (int m = 0; m < M_NODES; ++m) { qv[m] = qk[m]; qmax = fmaxf(qmax, qv[m]); }
        float qs = 0.f;
#pragma unroll
        for (int m = 0; m < M_NODES; ++m) {
            qv[m] = (qv[m] - qmax) * LOG2E;
            qs += EXP2F(qv[m]);
        }
        const float corr = LOG2F(qs);
#pragma unroll
        for (int mm = 0; mm < M2; ++mm)
            lblav[p][mm] = (v2f){qv[2 * mm] - corr - la2, qv[2 * mm + 1] - corr - la2};
    }

    bool act[NMAX];
#pragma unroll
    for (int i = 0; i < NMAX; ++i) act[i] = (lane + i * 64) < count;

    // Lv[p][i][mm] = (negC*log2e) - nsh_i, as v2f pairs (log domain, <= 0)
    v2f Lv[NPROB][NMAX][M2];
    float nsum[NPROB];
    v2f cshv[NPROB][M2];
    {
        const float* Tk0 = tplt + (size_t)k0 * M_NODES * DFEAT;
        const float* Tk1 = tplt + (size_t)(k0 + 8) * M_NODES * DFEAT;
        float x2[NMAX];
        v2f t2v[NPROB][M2];
#pragma unroll
        for (int i = 0; i < NMAX; ++i) {
            x2[i] = 0.f;
#pragma unroll
            for (int p = 0; p < NPROB; ++p)
#pragma unroll
                for (int mm = 0; mm < M2; ++mm) Lv[p][i][mm] = (v2f){0.f, 0.f};
        }
#pragma unroll
        for (int p = 0; p < NPROB; ++p)
#pragma unroll
            for (int mm = 0; mm < M2; ++mm) t2v[p][mm] = (v2f){0.f, 0.f};

        for (int j = 0; j < DFEAT; j += 4) {
            float4 xv[NMAX];
#pragma unroll
            for (int i = 0; i < NMAX; ++i) {
                if (act[i]) {
                    xv[i] = *(const float4*)(x + (size_t)(start + lane + i * 64) * DFEAT + j);
                } else {
                    xv[i].x = xv[i].y = xv[i].z = xv[i].w = 0.f;
                }
                x2[i] += dot4(xv[i], xv[i]);
            }
#pragma unroll
            for (int mm = 0; mm < M2; ++mm) {
                const float4 ta0 = *(const float4*)(Tk0 + (2 * mm)     * DFEAT + j);
                const float4 tb0 = *(const float4*)(Tk0 + (2 * mm + 1) * DFEAT + j);
                const float4 ta1 = *(const float4*)(Tk1 + (2 * mm)     * DFEAT + j);
                const float4 tb1 = *(const float4*)(Tk1 + (2 * mm + 1) * DFEAT + j);
                t2v[0][mm] += (v2f){dot4(ta0, ta0), dot4(tb0, tb0)};
                t2v[1][mm] += (v2f){dot4(ta1, ta1), dot4(tb1, tb1)};
#pragma unroll
                for (int i = 0; i < NMAX; ++i) {
                    Lv[0][i][mm] += (v2f){dot4(xv[i], ta0), dot4(xv[i], tb0)};
                    Lv[1][i][mm] += (v2f){dot4(xv[i], ta1), dot4(xv[i], tb1)};
                }
            }
        }
#pragma unroll
        for (int p = 0; p < NPROB; ++p) {
            nsum[p] = 0.f;
#pragma unroll
            for (int i = 0; i < NMAX; ++i) {
                const v2f x2v = {x2[i], x2[i]};
                v2f mxv = (v2f){NEG_BIG, NEG_BIG};
#pragma unroll
                for (int mm = 0; mm < M2; ++mm) {
                    Lv[p][i][mm] = (Lv[p][i][mm] * 2.f - x2v - t2v[p][mm]) * LOG2E; // negC2
                    mxv = v2max(mxv, Lv[p][i][mm]);
                }
                const float mx = fmaxf(mxv.x, mxv.y);
                if (act[i]) nsum[p] += mx;
                const v2f mxb = {mx, mx};
#pragma unroll
                for (int mm = 0; mm < M2; ++mm) Lv[p][i][mm] -= mxb;   // <= 0
            }
            // per-column max over active entries (setup-only, shfl path)
            float csh[M_NODES];
#pragma unroll
            for (int m = 0; m < M_NODES; ++m) {
                float c = NEG_BIG;
#pragma unroll
                for (int i = 0; i < NMAX; ++i) {
                    const float lv = (m & 1) ? Lv[p][i][m >> 1].y : Lv[p][i][m >> 1].x;
                    c = act[i] ? fmaxf(c, lv) : c;
                }
                csh[m] = wred_max(c);
            }
#pragma unroll
            for (int mm = 0; mm < M2; ++mm) cshv[p][mm] = (v2f){csh[2 * mm], csh[2 * mm + 1]};
        }
    }

    v2f g2v[NPROB][M2];

    // ---- iteration 1: g = 0, exact with per-column shift csh ----
#pragma unroll
    for (int p = 0; p < NPROB; ++p) {
        v2f w0v[M2], acc[M2];
#pragma unroll
        for (int mm = 0; mm < M2; ++mm) {
            w0v[mm] = (v2f){EXP2F(cshv[p][mm].x), EXP2F(cshv[p][mm].y)};
            acc[mm] = (v2f){0.f, 0.f};
        }
#pragma unroll
        for (int i = 0; i < NMAX; ++i) {
            if (act[i]) {
                v2f Ev[M2];
                v2f Dp = (v2f){0.f, 0.f};
#pragma unroll
                for (int mm = 0; mm < M2; ++mm) {
                    Ev[mm] = (v2f){EXP2F(Lv[p][i][mm].x - cshv[p][mm].x),
                                   EXP2F(Lv[p][i][mm].y - cshv[p][mm].y)};
                    Dp += Ev[mm] * w0v[mm];              // = sum 2^L per pair
                }
                const float D = Dp.x + Dp.y;             // >= 1
                const float r = __builtin_amdgcn_rcpf(D);
                const v2f rv = {r, r};
#pragma unroll
                for (int mm = 0; mm < M2; ++mm) acc[mm] += Ev[mm] * rv;
            }
        }
#pragma unroll
        for (int mm = 0; mm < M2; ++mm) {
            const float s0 = wred_add_u(acc[mm].x);
            const float s1 = wred_add_u(acc[mm].y);
            g2v[p][mm].x = lblav[p][mm].x - cshv[p][mm].x - LOG2F(fmaxf(s0, 1e-35f));
            g2v[p][mm].y = lblav[p][mm].y - cshv[p][mm].y - LOG2F(fmaxf(s1, 1e-35f));
        }
    }

    // ---- iterations 2..N_ITER: fresh per-node row shift each time ----
    for (int it = 1; it < N_ITER; ++it) {
        v2f acc[NPROB][M2];
#pragma unroll
        for (int p = 0; p < NPROB; ++p)
#pragma unroll
            for (int mm = 0; mm < M2; ++mm) acc[p][mm] = (v2f){0.f, 0.f};

#pragma unroll
        for (int i = 0; i < NMAX; ++i) {
            if (act[i]) {
#pragma unroll
                for (int p = 0; p < NPROB; ++p) {
                    v2f z[M2];
#pragma unroll
                    for (int mm = 0; mm < M2; ++mm) z[mm] = g2v[p][mm] + Lv[p][i][mm];
                    v2f mzv = v2max(z[0], z[1]);
                    mzv = v2max(mzv, z[2]);
                    mzv = v2max(mzv, z[3]);
                    mzv = v2max(mzv, z[4]);
                    const float zmax = fmaxf(mzv.x, mzv.y);
                    const v2f zb = {zmax, zmax};
                    v2f e[M2];
                    v2f Dp = (v2f){0.f, 0.f};
#pragma unroll
                    for (int mm = 0; mm < M2; ++mm) {
                        const v2f d = z[mm] - zb;
                        e[mm] = (v2f){EXP2F(d.x), EXP2F(d.y)};
                        Dp += e[mm];
                    }
                    const float D = Dp.x + Dp.y;         // in [1,10]
                    const float r = __builtin_amdgcn_rcpf(D);
                    const v2f rv = {r, r};
#pragma unroll
                    for (int mm = 0; mm < M2; ++mm) acc[p][mm] += e[mm] * rv;
                }
            }
        }
#pragma unroll
        for (int p = 0; p < NPROB; ++p)
#pragma unroll
            for (int mm = 0; mm < M2; ++mm) {
                const float s0 = wred_add_u(acc[p][mm].x);
                const float s1 = wred_add_u(acc[p][mm].y);
                g2v[p][mm].x = lblav[p][mm].x + g2v[p][mm].x - LOG2F(fmaxf(s0, 1e-35f));
                g2v[p][mm].y = lblav[p][mm].y + g2v[p][mm].y - LOG2F(fmaxf(s1, 1e-35f));
            }
    }

    // ---- epilogue: final f fused with transport cost ----
    // per_node = -a*ln2*( nsh_i + r * sum_m e_m L_m ); nsh pre-summed in nsum
#pragma unroll
    for (int p = 0; p < NPROB; ++p) {
        float accum = nsum[p];
#pragma unroll
        for (int i = 0; i < NMAX; ++i) {
            if (act[i]) {
                v2f z[M2];
#pragma unroll
                for (int mm = 0; mm < M2; ++mm) z[mm] = g2v[p][mm] + Lv[p][i][mm];
                v2f mzv = v2max(z[0], z[1]);
                mzv = v2max(mzv, z[2]);
                mzv = v2max(mzv, z[3]);
                mzv = v2max(mzv, z[4]);
                const float zmax = fmaxf(mzv.x, mzv.y);
                const v2f zb = {zmax, zmax};
                v2f e[M2];
                v2f Dp = (v2f){0.f, 0.f};
                v2f qv = (v2f){0.f, 0.f};
#pragma unroll
                for (int mm = 0; mm < M2; ++mm) {
                    const v2f d = z[mm] - zb;
                    e[mm] = (v2f){EXP2F(d.x), EXP2F(d.y)};
                    Dp += e[mm];
                    qv += e[mm] * Lv[p][i][mm];
                }
                const float D = Dp.x + Dp.y;
                const float r = __builtin_amdgcn_rcpf(D);
                accum += (qv.x + qv.y) * r;
            }
        }
        accum = wred_add_u(accum);
        if (lane == 0) out[(size_t)g * K_TPLT + (k0 + 8 * p)] = -a * LN2 * accum;
    }
}

extern "C" void kernel_launch(void* const* d_in, const int* in_sizes, int n_in,
                              void* d_out, int out_size, void* d_ws, size_t ws_size,
                              hipStream_t stream) {
    const float* x    = (const float*)d_in[0];
    const float* tplt = (const float*)d_in[1];
    const float* q0   = (const float*)d_in[2];
    const int* batch  = (const int*)d_in[3];
    const int N = in_sizes[3];
    const int G = out_size / K_TPLT;

    int* counts = (int*)d_ws;
    int* starts = counts + G;

    zero_counts_k<<<(G + 255) / 256, 256, 0, stream>>>(counts, G);
    count_nodes_k<<<(N + 255) / 256, 256, 0, stream>>>(batch, counts, N);
    scan_counts_k<<<1, 256, 0, stream>>>(counts, starts, G);
    sinkhorn_tw_k<<<G * (K_TPLT / 2), 64, 0, stream>>>(x, tplt, q0, starts, counts,
                                                       (float*)d_out, G);
}